// Round 16
// baseline (4749.435 us; speedup 1.0000x reference)
//
#include <hip/hip_runtime.h>
#include <math.h>

// Problem constants
static constexpr int H   = 512;
static constexpr int B   = 32;
static constexpr int S   = 128;
static constexpr int G4  = 2048;  // 4*H
static constexpr int UPS = 64;    // units per y-slice
static constexpr int RPS = 256;   // rows per y-slice (4 gates * UPS)
static constexpr int NSL = 8;     // y-slices per batch

// ws layout (floats)
static constexpr size_t OFF_E   = 0;                          // E [b][t][c]; reused as D
static constexpr size_t SZ_E    = (size_t)B * S * G4;
static constexpr size_t OFF_EO  = OFF_E + SZ_E;               // enc_out [b][t][h]
static constexpr size_t SZ_EO   = (size_t)B * S * H;
static constexpr size_t OFF_PT  = OFF_EO + SZ_EO;             // P_t [b][h][s]
static constexpr size_t SZ_PT   = (size_t)B * H * S;
static constexpr size_t OFF_WPE = OFF_PT + SZ_PT;             // packed enc Whh [8][512][256]
static constexpr size_t SZ_WP   = (size_t)NSL * H * RPS;
static constexpr size_t OFF_WPD = OFF_WPE + SZ_WP;            // packed dec Whh
static constexpr size_t OFF_W2T = OFF_WPD + SZ_WP;            // W2T [512][512]
static constexpr size_t OFF_HB  = OFF_W2T + (size_t)H * H;    // hb [B][2][H]
static constexpr size_t OFF_CB  = OFF_HB + (size_t)B * 2 * H; // c_buf [B][H]
static constexpr size_t OFF_PS  = OFF_CB + (size_t)B * H;     // psbuf [B][2][8][128]
static constexpr size_t SZ_PS   = (size_t)B * 2 * 8 * 128;
static constexpr size_t OFF_M1  = OFF_PS + SZ_PS;
static constexpr size_t OFF_BE  = OFF_M1 + (size_t)G4 * 2;
static constexpr size_t OFF_DB  = OFF_BE + G4;
static constexpr size_t OFF_END = OFF_DB + G4;
// u32 ctrl: enc_htags[256], dec_htags[256], pstags[256] (x32-u32 lines)
static constexpr int CTRL_U32 = (256 + 256 + 256) * 32;

// weight-cache split (kk = k-quad index, 128 total)
static constexpr int KR = 64;   // kk 0..63  -> registers (k-rows 0..255, 256KB/blk)
static constexpr int KL = 32;   // kk 64..95 -> LDS (k-rows 256..383, 128KB)
// kk 96..127 -> streamed from L2 (k-rows 384..511, 128KB)

__device__ __forceinline__ float sigm(float x){
  float e = __expf(-x);
  return 1.0f / (1.0f + e);
}
__device__ __forceinline__ float tanh_(float x){
  float e = __expf(2.0f * x);
  return 1.0f - 2.0f / (1.0f + e);
}

// agent-scope (coherence-point) accessors; discipline: __syncthreads (vmcnt
// drain) between data stores and the tag store (validated r2-r15)
__device__ __forceinline__ float cloadf(const float* p){
  union { unsigned u; float f; } c;
  c.u = __hip_atomic_load((const unsigned*)p, __ATOMIC_RELAXED,
                          __HIP_MEMORY_SCOPE_AGENT);
  return c.f;
}
__device__ __forceinline__ float2 cload2(const float* p){
  union { unsigned long long u; float2 f; } c;
  c.u = __hip_atomic_load((const unsigned long long*)p, __ATOMIC_RELAXED,
                          __HIP_MEMORY_SCOPE_AGENT);
  return c.f;
}
__device__ __forceinline__ void cstore2(float* p, float a, float b){
  union { unsigned long long u; float2 f; } c;
  c.f = make_float2(a, b);
  __hip_atomic_store((unsigned long long*)p, c.u, __ATOMIC_RELAXED,
                     __HIP_MEMORY_SCOPE_AGENT);
}
__device__ __forceinline__ unsigned cloadu(const unsigned* p){
  return __hip_atomic_load(p, __ATOMIC_RELAXED, __HIP_MEMORY_SCOPE_AGENT);
}
__device__ __forceinline__ void cstoreu(unsigned* p, unsigned v){
  __hip_atomic_store(p, v, __ATOMIC_RELAXED, __HIP_MEMORY_SCOPE_AGENT);
}

// -------- prep: M1 = Wih@Wp, bias_e = Wih@bp + bih + bhh, dbias --------
__global__ __launch_bounds__(256) void prep_misc(
    const float* __restrict__ eWih, const float* __restrict__ Wp,
    const float* __restrict__ bp,  const float* __restrict__ ebih,
    const float* __restrict__ ebhh, const float* __restrict__ dbih,
    const float* __restrict__ dbhh,
    float* __restrict__ M1, float* __restrict__ bias_e, float* __restrict__ dbias)
{
  int c = blockIdx.x * 256 + threadIdx.x;
  const float* wr = eWih + (size_t)c * H;
  float m0 = 0.f, m1 = 0.f, mb = 0.f;
  for (int k = 0; k < H; k += 4){
    float4 w  = *(const float4*)(wr + k);
    float4 p0 = *(const float4*)(Wp + (size_t)k * 2);
    float4 p1 = *(const float4*)(Wp + (size_t)(k + 2) * 2);
    float4 bb = *(const float4*)(bp + k);
    m0 += w.x*p0.x + w.y*p0.z + w.z*p1.x + w.w*p1.z;
    m1 += w.x*p0.y + w.y*p0.w + w.z*p1.y + w.w*p1.w;
    mb += w.x*bb.x + w.y*bb.y + w.z*bb.z + w.w*bb.w;
  }
  M1[(size_t)c*2]   = m0;
  M1[(size_t)c*2+1] = m1;
  bias_e[c] = ebih[c] + ebhh[c] + mb;
  dbias[c]  = dbih[c] + dbhh[c];
}

// -------- E fill: E[b][t][c] = M1[c]·in[b,t] + bias_e[c] --------
__global__ __launch_bounds__(256) void efill(
    const float* __restrict__ inp, const float* __restrict__ M1,
    const float* __restrict__ be, float* __restrict__ E)
{
  size_t i = (size_t)blockIdx.x * 256 + threadIdx.x;
  int c = (int)(i & 2047);
  int t = (int)((i >> 11) & 127);
  int b = (int)(i >> 18);
  float x0 = inp[((size_t)b * S + t) * 2 + 0];
  float x1 = inp[((size_t)b * S + t) * 2 + 1];
  E[i] = M1[(size_t)c*2] * x0 + M1[(size_t)c*2+1] * x1 + be[c];
}

// -------- pack Whh into per-slice contiguous form WP[j][k][g*64+u] --------
__global__ __launch_bounds__(256) void pack_whh(
    const float* __restrict__ Whh, float* __restrict__ WP)
{
  size_t i = (size_t)blockIdx.x * 256 + threadIdx.x;
  int p = (int)(i & 255);
  int k = (int)((i >> 8) & 511);
  int j = (int)(i >> 17);
  int g = p >> 6, u = p & 63;
  int r = g * 512 + j * UPS + u;
  WP[i] = Whh[(size_t)r * H + k];
}

// -------- transpose: out[K][R] = in[R][K] --------
__global__ __launch_bounds__(256) void transpose_k(
    const float* __restrict__ in, float* __restrict__ out, int R, int K)
{
  __shared__ float tile[32][33];
  int r0 = blockIdx.y * 32, k0 = blockIdx.x * 32;
  int tx = threadIdx.x & 31, ty = threadIdx.x >> 5;
  #pragma unroll
  for (int j = 0; j < 4; ++j)
    tile[ty + 8*j][tx] = in[(size_t)(r0 + ty + 8*j) * K + k0 + tx];
  __syncthreads();
  #pragma unroll
  for (int j = 0; j < 4; ++j)
    out[(size_t)(k0 + ty + 8*j) * R + r0 + tx] = tile[tx][ty + 8*j];
}

// -------- generic fp32 GEMM: C = A(MxK) @ B(NxK)^T (+bias) --------
template<int LAYOUT>
__global__ __launch_bounds__(256) void gemm_nt(
    const float* __restrict__ A, const float* __restrict__ Bm,
    const float* __restrict__ bias, float* __restrict__ C,
    int M, int N, int K)
{
  __shared__ float As[16][68];
  __shared__ float Bs[16][68];
  int tid = threadIdx.x;
  int bm = blockIdx.y * 64, bn = blockIdx.x * 64;
  int tm = (tid & 15) * 4, tn = (tid >> 4) * 4;
  float acc[4][4] = {};
  int r  = tid >> 2;
  int kq = (tid & 3) * 4;
  for (int k0 = 0; k0 < K; k0 += 16){
    float4 a = *(const float4*)(A  + (size_t)(bm + r) * K + k0 + kq);
    float4 b = *(const float4*)(Bm + (size_t)(bn + r) * K + k0 + kq);
    __syncthreads();
    As[kq+0][r] = a.x; As[kq+1][r] = a.y; As[kq+2][r] = a.z; As[kq+3][r] = a.w;
    Bs[kq+0][r] = b.x; Bs[kq+1][r] = b.y; Bs[kq+2][r] = b.z; Bs[kq+3][r] = b.w;
    __syncthreads();
    #pragma unroll
    for (int kk = 0; kk < 16; ++kk){
      float4 av = *(const float4*)(&As[kk][tm]);
      float4 bv = *(const float4*)(&Bs[kk][tn]);
      acc[0][0] += av.x*bv.x; acc[0][1] += av.x*bv.y; acc[0][2] += av.x*bv.z; acc[0][3] += av.x*bv.w;
      acc[1][0] += av.y*bv.x; acc[1][1] += av.y*bv.y; acc[1][2] += av.y*bv.z; acc[1][3] += av.y*bv.w;
      acc[2][0] += av.z*bv.x; acc[2][1] += av.z*bv.y; acc[2][2] += av.z*bv.z; acc[2][3] += av.z*bv.w;
      acc[3][0] += av.w*bv.x; acc[3][1] += av.w*bv.y; acc[3][2] += av.w*bv.z; acc[3][3] += av.w*bv.w;
    }
  }
  #pragma unroll
  for (int i = 0; i < 4; ++i){
    int m = bm + tm + i;
    #pragma unroll
    for (int j = 0; j < 4; ++j){
      int n = bn + tn + j;
      float vv = acc[i][j] + (bias ? bias[n] : 0.f);
      if (LAYOUT == 0) C[(size_t)m * N + n] = vv;
      else             C[((size_t)(m >> 7) * 512 + n) * 128 + (m & 127)] = vv;
    }
  }
}

// gemv with 3-way weight source: regs (kk<KR), LDS (KR..KR+KL), L2 (rest)
__device__ __forceinline__ float4 gemv_split(
    const float4* wreg, const float* wlds, const float* wp,
    const float* hsh, int ph, int c4)
{
  float4 acc = {0.f, 0.f, 0.f, 0.f};
  #pragma unroll
  for (int kk = 0; kk < KR; ++kk){
    float hv = hsh[4*kk + ph];
    float4 w = wreg[kk];
    acc.x = fmaf(w.x, hv, acc.x); acc.y = fmaf(w.y, hv, acc.y);
    acc.z = fmaf(w.z, hv, acc.z); acc.w = fmaf(w.w, hv, acc.w);
  }
  #pragma unroll 4
  for (int kk = KR; kk < KR + KL; ++kk){
    float hv = hsh[4*kk + ph];
    float4 w = *(const float4*)&wlds[((4*kk + ph) - 4*KR) * RPS + c4*4];
    acc.x = fmaf(w.x, hv, acc.x); acc.y = fmaf(w.y, hv, acc.y);
    acc.z = fmaf(w.z, hv, acc.z); acc.w = fmaf(w.w, hv, acc.w);
  }
  const float* wq = wp + (size_t)(4*(KR+KL)) * RPS + ph * RPS + c4 * 4;
  #pragma unroll 4
  for (int kk = KR + KL; kk < 128; ++kk){
    float hv = hsh[4*kk + ph];
    float4 w = *(const float4*)(wq + (size_t)(kk - KR - KL) * 4 * RPS);
    acc.x = fmaf(w.x, hv, acc.x); acc.y = fmaf(w.y, hv, acc.y);
    acc.z = fmaf(w.z, hv, acc.z); acc.w = fmaf(w.w, hv, acc.w);
  }
  return acc;
}

// -------- encoder: grid=256 (1 block/CU), weight-cached gemv --------
// __launch_bounds__(256,1): 1 wave/SIMD => VGPR budget ~512, no spill for
// wreg[64] (r15 lesson: default bounds cap at ~168 and spill to scratch).
__global__ __launch_bounds__(256, 1) void encoder_kernel(
    const float* __restrict__ WP,     // [8][512][256]
    const float* __restrict__ E,      // [b][t][2048]
    float* __restrict__ hb,           // [B][2][H] (zeroed)
    float* __restrict__ c_buf,        // [B][H]
    float* __restrict__ enc_out,      // [b][t][h]
    unsigned* __restrict__ htags)     // 256 lines, (b*8+j)*32
{
  __shared__ float wlds[KL * 4 * RPS];   // 128KB
  __shared__ float hsh[H];
  __shared__ float gpart[4][RPS];
  __shared__ float gfin[4][UPS];
  __shared__ float hloc[UPS];
  const int tid = threadIdx.x, bk = blockIdx.x;
  const int b = bk >> 3, j = bk & 7;
  const int u0 = j * UPS;
  const float* wp = WP + (size_t)j * H * RPS;
  unsigned* myhtags = htags + (size_t)b * 8 * 32;
  const int ph = tid >> 6, c4 = tid & 63;
  for (int i = tid; i < KL * RPS; i += 256)
    *(float4*)&wlds[i*4] = *(const float4*)(wp + (size_t)(4*KR) * RPS + (size_t)i*4);
  float4 wreg[KR];
  #pragma unroll
  for (int kk = 0; kk < KR; ++kk)
    wreg[kk] = *(const float4*)(wp + (size_t)(4*kk + ph) * RPS + c4*4);
  float creg = 0.f;
  for (int t = 0; t < S; ++t){
    if (t > 0 && tid < 8){
      while (cloadu(myhtags + tid * 32) < (unsigned)t){}
    }
    __syncthreads();
    { float2 q = cload2(hb + ((size_t)b * 2 + ((t + 1) & 1)) * H + 2 * tid);
      hsh[2*tid] = q.x; hsh[2*tid + 1] = q.y; }
    __syncthreads();
    float4 acc = gemv_split(wreg, wlds, wp, hsh, ph, c4);
    *(float4*)&gpart[ph][c4 * 4] = acc;
    __syncthreads();
    if (tid < 64){
      float4 s0 = *(const float4*)&gpart[0][tid*4];
      float4 s1 = *(const float4*)&gpart[1][tid*4];
      float4 s2 = *(const float4*)&gpart[2][tid*4];
      float4 s3 = *(const float4*)&gpart[3][tid*4];
      int g = tid >> 4, uu = (tid & 15) * 4;
      float4 e = *(const float4*)(E + ((size_t)b * S + t) * G4 + g * 512 + u0 + uu);
      float4 s; s.x = s0.x+s1.x+s2.x+s3.x + e.x; s.y = s0.y+s1.y+s2.y+s3.y + e.y;
      s.z = s0.z+s1.z+s2.z+s3.z + e.z; s.w = s0.w+s1.w+s2.w+s3.w + e.w;
      *(float4*)&gfin[g][uu] = s;
    }
    __syncthreads();
    if (tid < UPS){
      float gi = gfin[0][tid], gf = gfin[1][tid], gg = gfin[2][tid], go = gfin[3][tid];
      creg = sigm(gf) * creg + sigm(gi) * tanh_(gg);
      hloc[tid] = sigm(go) * tanh_(creg);
    }
    __syncthreads();
    if (tid < 32){
      float h0 = hloc[2*tid], h1 = hloc[2*tid + 1];
      cstore2(hb + ((size_t)b * 2 + (t & 1)) * H + u0 + 2*tid, h0, h1);
      *(float2*)(enc_out + ((size_t)b * S + t) * H + u0 + 2*tid) = make_float2(h0, h1);
    }
    __syncthreads();   // drain publishes before tag
    if (tid == 0) cstoreu(myhtags + j * 32, (unsigned)(t + 1));
  }
  if (tid < UPS) c_buf[(size_t)b * H + u0 + tid] = creg;
}

// -------- decoder: fused y-blocks only, grid=256, weight-cached gemv --------
// Structure and safety arguments identical to r14; KR=64 with (256,1) bounds.
__global__ __launch_bounds__(256, 1) void decoder_kernel(
    const float* __restrict__ WP,     // [8][512][256] packed dec Whh
    const float* __restrict__ D,      // [b][t][2048]
    const float* __restrict__ dbias,  // [2048]
    const float* __restrict__ W2T,    // [512][512]
    const float* __restrict__ Pt,     // [b][h][s]
    const float* __restrict__ vvec,   // [512]
    const float* __restrict__ c_buf,  // [B][H]
    const float* __restrict__ enc_out,// [b][t][h]
    float* __restrict__ hb,           // [B][2][H]
    float* __restrict__ psbuf,        // [B][2][8][128]
    unsigned* __restrict__ htags,     // 256 lines
    unsigned* __restrict__ pstags,    // 256 lines
    float* __restrict__ out)          // [b][t][s]
{
  __shared__ float wlds[KL * 4 * RPS];   // 128KB
  __shared__ float hsh[H];
  __shared__ float gpart[4][RPS];
  __shared__ float gfin[4][UPS];
  __shared__ float hloc[UPS];
  __shared__ float dps[4][UPS];
  __shared__ float dpl[UPS];
  __shared__ float vsh[UPS];
  __shared__ float pspart[2][128];
  __shared__ float wm[2]; __shared__ int wi[2]; __shared__ float wsum[2];
  const int tid = threadIdx.x, bk = blockIdx.x;
  const int b = bk >> 3, j = bk & 7;
  const int u0 = j * UPS;
  const float* wp = WP + (size_t)j * H * RPS;
  unsigned* myhtags  = htags  + (size_t)b * 8 * 32;
  unsigned* mypstags = pstags + (size_t)b * 8 * 32;
  const int ph = tid >> 6, c4 = tid & 63;
  for (int i = tid; i < KL * RPS; i += 256)
    *(float4*)&wlds[i*4] = *(const float4*)(wp + (size_t)(4*KR) * RPS + (size_t)i*4);
  float4 wreg[KR];
  #pragma unroll
  for (int kk = 0; kk < KR; ++kk)
    wreg[kk] = *(const float4*)(wp + (size_t)(4*kk + ph) * RPS + c4*4);
  float creg = (tid < UPS) ? c_buf[(size_t)b * H + u0 + tid] : 0.f;
  if (tid < UPS) vsh[tid] = vvec[u0 + tid];
  if (tid < 32){
    float2 hv = *(const float2*)(enc_out + ((size_t)b * S + (S-1)) * H + u0 + 2*tid);
    cstore2(hb + ((size_t)b * 2 + 1) * H + u0 + 2*tid, hv.x, hv.y);
  }
  __syncthreads();
  if (tid == 0) cstoreu(myhtags + j * 32, 1u);
  for (int t = 0; t < S; ++t){
    if (tid < 8){
      while (cloadu(myhtags + tid * 32) < (unsigned)(t + 1)) __builtin_amdgcn_s_sleep(1);
    }
    __syncthreads();
    { float2 q = cload2(hb + ((size_t)b * 2 + ((t + 1) & 1)) * H + 2 * tid);
      hsh[2*tid] = q.x; hsh[2*tid + 1] = q.y; }
    __syncthreads();
    if (t >= 1){
      {
        int nl = tid & 63, kq = tid >> 6;
        const float* w = W2T + (size_t)(kq * 128) * H + u0 + nl;
        float a = 0.f;
        #pragma unroll 8
        for (int k2 = 0; k2 < 128; ++k2)
          a = fmaf(w[(size_t)k2 * H], hsh[kq * 128 + k2], a);
        dps[kq][nl] = a;
      }
      __syncthreads();
      if (tid < UPS) dpl[tid] = dps[0][tid] + dps[1][tid] + dps[2][tid] + dps[3][tid];
      __syncthreads();
      {
        int s = tid & 127, nh = tid >> 7;
        const float* Pp = Pt + ((size_t)b * H + u0 + nh * 32) * S + s;
        float cs = 0.f;
        #pragma unroll 4
        for (int n = 0; n < 32; ++n){
          float x = Pp[(size_t)n * S] + dpl[nh * 32 + n];
          cs = fmaf(vsh[nh * 32 + n], tanh_(x), cs);
        }
        pspart[nh][s] = cs;
      }
      __syncthreads();
      if (tid < 64)
        cstore2(psbuf + (((size_t)b * 2 + ((t - 1) & 1)) * 8 + j) * 128 + 2 * tid,
                pspart[0][2*tid] + pspart[1][2*tid],
                pspart[0][2*tid+1] + pspart[1][2*tid+1]);
      __syncthreads();   // drain ps publish before tag
      if (tid == 0) cstoreu(mypstags + j * 32, (unsigned)t);
    }
    float4 acc = gemv_split(wreg, wlds, wp, hsh, ph, c4);
    *(float4*)&gpart[ph][c4 * 4] = acc;
    if (t >= 1 && tid < 8){
      while (cloadu(mypstags + tid * 32) < (unsigned)t) __builtin_amdgcn_s_sleep(1);
    }
    __syncthreads();
    float sc = 0.f;
    if (t >= 1 && tid < 128){
      const float* pp = psbuf + ((size_t)b * 2 + ((t - 1) & 1)) * 8 * 128 + tid;
      #pragma unroll
      for (int jj2 = 0; jj2 < 8; ++jj2) sc += cloadf(pp + jj2 * 128);
      float mv = sc; int mi = tid;
      #pragma unroll
      for (int off = 32; off > 0; off >>= 1){
        float ov = __shfl_xor(mv, off, 64);
        int   oi = __shfl_xor(mi, off, 64);
        if (ov > mv || (ov == mv && oi < mi)){ mv = ov; mi = oi; }
      }
      if ((tid & 63) == 0){ wm[tid >> 6] = mv; wi[tid >> 6] = mi; }
    }
    __syncthreads();
    int top = 0; float mglob = 0.f;
    if (t >= 1){
      if (wm[1] > wm[0] || (wm[1] == wm[0] && wi[1] < wi[0])){ top = wi[1]; mglob = wm[1]; }
      else { top = wi[0]; mglob = wm[0]; }
    }
    if (tid < 64){
      float4 s0 = *(const float4*)&gpart[0][tid*4];
      float4 s1 = *(const float4*)&gpart[1][tid*4];
      float4 s2 = *(const float4*)&gpart[2][tid*4];
      float4 s3 = *(const float4*)&gpart[3][tid*4];
      int g = tid >> 4, uu = (tid & 15) * 4;
      const float* xr = (t == 0) ? dbias : D + ((size_t)b * S + top) * G4;
      float4 e = *(const float4*)(xr + g * 512 + u0 + uu);
      float4 s; s.x = s0.x+s1.x+s2.x+s3.x + e.x; s.y = s0.y+s1.y+s2.y+s3.y + e.y;
      s.z = s0.z+s1.z+s2.z+s3.z + e.z; s.w = s0.w+s1.w+s2.w+s3.w + e.w;
      *(float4*)&gfin[g][uu] = s;
    }
    __syncthreads();
    if (tid < UPS){
      float gi = gfin[0][tid], gf = gfin[1][tid], gg = gfin[2][tid], go = gfin[3][tid];
      creg = sigm(gf) * creg + sigm(gi) * tanh_(gg);
      hloc[tid] = sigm(go) * tanh_(creg);
    }
    __syncthreads();
    if (tid < 32)
      cstore2(hb + ((size_t)b * 2 + (t & 1)) * H + u0 + 2*tid,
              hloc[2*tid], hloc[2*tid + 1]);
    __syncthreads();   // drain h publish before tag
    if (tid == 0) cstoreu(myhtags + j * 32, (unsigned)(t + 2));
    // rotating softmax duty (off the h critical path)
    if (t >= 1 && j == ((t - 1) & 7)){
      if (tid < 128){
        float ss = __expf(sc - mglob);
        #pragma unroll
        for (int off = 32; off > 0; off >>= 1) ss += __shfl_xor(ss, off, 64);
        if ((tid & 63) == 0) wsum[tid >> 6] = ss;
      }
      __syncthreads();
      if (tid < 128){
        float lse = __logf(wsum[0] + wsum[1]);
        out[((size_t)b * S + (t - 1)) * S + tid] = sc - mglob - lse;
      }
    }
  }
  // -------- epilogue: ps(127) + final softmax row 127 --------
  if (tid < 8){
    while (cloadu(myhtags + tid * 32) < (unsigned)(S + 1)) __builtin_amdgcn_s_sleep(1);
  }
  __syncthreads();
  { float2 q = cload2(hb + ((size_t)b * 2 + 1) * H + 2 * tid);
    hsh[2*tid] = q.x; hsh[2*tid + 1] = q.y; }
  __syncthreads();
  {
    int nl = tid & 63, kq = tid >> 6;
    const float* w = W2T + (size_t)(kq * 128) * H + u0 + nl;
    float a = 0.f;
    #pragma unroll 8
    for (int k2 = 0; k2 < 128; ++k2)
      a = fmaf(w[(size_t)k2 * H], hsh[kq * 128 + k2], a);
    dps[kq][nl] = a;
  }
  __syncthreads();
  if (tid < UPS) dpl[tid] = dps[0][tid] + dps[1][tid] + dps[2][tid] + dps[3][tid];
  __syncthreads();
  {
    int s = tid & 127, nh = tid >> 7;
    const float* Pp = Pt + ((size_t)b * H + u0 + nh * 32) * S + s;
    float cs = 0.f;
    #pragma unroll 4
    for (int n = 0; n < 32; ++n){
      float x = Pp[(size_t)n * S] + dpl[nh * 32 + n];
      cs = fmaf(vsh[nh * 32 + n], tanh_(x), cs);
    }
    pspart[nh][s] = cs;
  }
  __syncthreads();
  if (tid < 64)
    cstore2(psbuf + (((size_t)b * 2 + ((S - 1) & 1)) * 8 + j) * 128 + 2 * tid,
            pspart[0][2*tid] + pspart[1][2*tid],
            pspart[0][2*tid+1] + pspart[1][2*tid+1]);
  __syncthreads();
  if (tid == 0) cstoreu(mypstags + j * 32, (unsigned)S);
  if (j == 7){
    if (tid < 8){
      while (cloadu(mypstags + tid * 32) < (unsigned)S) __builtin_amdgcn_s_sleep(1);
    }
    __syncthreads();
    float sc = 0.f;
    if (tid < 128){
      const float* pp = psbuf + ((size_t)b * 2 + ((S - 1) & 1)) * 8 * 128 + tid;
      #pragma unroll
      for (int jj2 = 0; jj2 < 8; ++jj2) sc += cloadf(pp + jj2 * 128);
      float mv = sc;
      #pragma unroll
      for (int off = 32; off > 0; off >>= 1)
        mv = fmaxf(mv, __shfl_xor(mv, off, 64));
      if ((tid & 63) == 0) wm[tid >> 6] = mv;
    }
    __syncthreads();
    float mglob = fmaxf(wm[0], wm[1]);
    if (tid < 128){
      float ss = __expf(sc - mglob);
      #pragma unroll
      for (int off = 32; off > 0; off >>= 1) ss += __shfl_xor(ss, off, 64);
      if ((tid & 63) == 0) wsum[tid >> 6] = ss;
    }
    __syncthreads();
    if (tid < 128){
      float lse = __logf(wsum[0] + wsum[1]);
      out[((size_t)b * S + (S - 1)) * S + tid] = sc - mglob - lse;
    }
  }
}

extern "C" void kernel_launch(void* const* d_in, const int* in_sizes, int n_in,
                              void* d_out, int out_size, void* d_ws, size_t ws_size,
                              hipStream_t stream) {
  const float* inputs  = (const float*)d_in[0];
  const float* Wp      = (const float*)d_in[1];
  const float* bp      = (const float*)d_in[2];
  const float* eWih    = (const float*)d_in[3];
  const float* eWhh    = (const float*)d_in[4];
  const float* ebih    = (const float*)d_in[5];
  const float* ebhh    = (const float*)d_in[6];
  const float* dWih    = (const float*)d_in[7];
  const float* dWhh    = (const float*)d_in[8];
  const float* dbih    = (const float*)d_in[9];
  const float* dbhh    = (const float*)d_in[10];
  const float* W1      = (const float*)d_in[11];
  const float* W2      = (const float*)d_in[12];
  const float* v       = (const float*)d_in[13];
  float* out = (float*)d_out;

  float* ws = (float*)d_ws;
  float* E       = ws + OFF_E;    // reused as D after encoder
  float* enc_out = ws + OFF_EO;
  float* Pt      = ws + OFF_PT;
  float* WPe     = ws + OFF_WPE;
  float* WPd     = ws + OFF_WPD;
  float* W2T     = ws + OFF_W2T;
  float* hb      = ws + OFF_HB;
  float* c_buf   = ws + OFF_CB;
  float* psbuf   = ws + OFF_PS;
  float* M1      = ws + OFF_M1;
  float* bias_e  = ws + OFF_BE;
  float* dbias   = ws + OFF_DB;
  unsigned* enc_htags = (unsigned*)(ws + OFF_END);
  unsigned* dec_htags = enc_htags + 256 * 32;
  unsigned* pstags    = dec_htags + 256 * 32;

  hipMemsetAsync(hb, 0, (size_t)B * 2 * H * sizeof(float), stream);
  hipMemsetAsync(enc_htags, 0, CTRL_U32 * sizeof(unsigned), stream);

  prep_misc<<<G4 / 256, 256, 0, stream>>>(eWih, Wp, bp, ebih, ebhh, dbih, dbhh,
                                          M1, bias_e, dbias);
  efill<<<(int)(SZ_E / 256), 256, 0, stream>>>(inputs, M1, bias_e, E);
  pack_whh<<<(int)(SZ_WP / 256), 256, 0, stream>>>(eWhh, WPe);
  pack_whh<<<(int)(SZ_WP / 256), 256, 0, stream>>>(dWhh, WPd);
  { dim3 g(H / 32, H / 32); transpose_k<<<g, 256, 0, stream>>>(W2, W2T, H, H); }

  encoder_kernel<<<256, 256, 0, stream>>>(WPe, E, hb, c_buf, enc_out, enc_htags);

  float* D = E;
  { dim3 grid(G4 / 64, (B * S) / 64);
    gemm_nt<0><<<grid, 256, 0, stream>>>(enc_out, dWih, dbias, D, B * S, G4, H); }
  { dim3 grid(H / 64, (B * S) / 64);
    gemm_nt<1><<<grid, 256, 0, stream>>>(enc_out, W1, nullptr, Pt, B * S, H, H); }

  decoder_kernel<<<256, 256, 0, stream>>>(WPd, D, dbias, W2T, Pt, v, c_buf,
                                          enc_out, hb, psbuf,
                                          dec_htags, pstags, out);
  (void)in_sizes; (void)n_in; (void)out_size; (void)ws_size;
}

// Round 17
// 2923.924 us; speedup vs baseline: 1.6243x; 1.6243x over previous
//
#include <hip/hip_runtime.h>
#include <math.h>

// Problem constants
static constexpr int H   = 512;
static constexpr int B   = 32;
static constexpr int S   = 128;
static constexpr int G4  = 2048;  // 4*H
static constexpr int UPS = 64;    // units per y-slice
static constexpr int RPS = 256;   // rows per y-slice (4 gates * UPS)
static constexpr int NSL = 8;     // y-slices per batch

// ws layout (floats)
static constexpr size_t OFF_E   = 0;                          // E [b][t][c]; reused as D
static constexpr size_t SZ_E    = (size_t)B * S * G4;
static constexpr size_t OFF_EO  = OFF_E + SZ_E;               // enc_out [b][t][h]
static constexpr size_t SZ_EO   = (size_t)B * S * H;
static constexpr size_t OFF_PT  = OFF_EO + SZ_EO;             // P_t [b][h][s]
static constexpr size_t SZ_PT   = (size_t)B * H * S;
static constexpr size_t OFF_WPE = OFF_PT + SZ_PT;             // packed enc Whh [8][512][256]
static constexpr size_t SZ_WP   = (size_t)NSL * H * RPS;
static constexpr size_t OFF_WPD = OFF_WPE + SZ_WP;            // packed dec Whh
static constexpr size_t OFF_W2T = OFF_WPD + SZ_WP;            // W2T [512][512]
static constexpr size_t OFF_HB  = OFF_W2T + (size_t)H * H;    // hb [B][2][H]
static constexpr size_t OFF_CB  = OFF_HB + (size_t)B * 2 * H; // c_buf [B][H]
static constexpr size_t OFF_PS  = OFF_CB + (size_t)B * H;     // psbuf [B][2][8][128]
static constexpr size_t SZ_PS   = (size_t)B * 2 * 8 * 128;
static constexpr size_t OFF_M1  = OFF_PS + SZ_PS;
static constexpr size_t OFF_BE  = OFF_M1 + (size_t)G4 * 2;
static constexpr size_t OFF_DB  = OFF_BE + G4;
static constexpr size_t OFF_END = OFF_DB + G4;
// u32 ctrl: enc_htags[256], dec_htags[256], pstags[256] (x32-u32 lines)
static constexpr int CTRL_U32 = (256 + 256 + 256) * 32;

// weight-cache split (kk = k-quad index, 128 total). KR=32 is the proven
// no-spill config (r14: VGPR=132). KR=64 spills at VGPR cap 168 regardless
// of __launch_bounds__ (r15/r16 lesson) — do not revisit.
static constexpr int KR = 32;   // kk 0..31  -> registers (k-rows 0..127, 128KB/blk)
static constexpr int KL = 32;   // kk 32..63 -> LDS (k-rows 128..255, 128KB)
// kk 64..127 -> streamed from L2 (k-rows 256..511, 256KB)

__device__ __forceinline__ float sigm(float x){
  float e = __expf(-x);
  return 1.0f / (1.0f + e);
}
__device__ __forceinline__ float tanh_(float x){
  float e = __expf(2.0f * x);
  return 1.0f - 2.0f / (1.0f + e);
}

// agent-scope (coherence-point) accessors; discipline: __syncthreads (vmcnt
// drain) between data stores and the tag store (validated r2-r16)
__device__ __forceinline__ float cloadf(const float* p){
  union { unsigned u; float f; } c;
  c.u = __hip_atomic_load((const unsigned*)p, __ATOMIC_RELAXED,
                          __HIP_MEMORY_SCOPE_AGENT);
  return c.f;
}
__device__ __forceinline__ float2 cload2(const float* p){
  union { unsigned long long u; float2 f; } c;
  c.u = __hip_atomic_load((const unsigned long long*)p, __ATOMIC_RELAXED,
                          __HIP_MEMORY_SCOPE_AGENT);
  return c.f;
}
__device__ __forceinline__ void cstore2(float* p, float a, float b){
  union { unsigned long long u; float2 f; } c;
  c.f = make_float2(a, b);
  __hip_atomic_store((unsigned long long*)p, c.u, __ATOMIC_RELAXED,
                     __HIP_MEMORY_SCOPE_AGENT);
}
__device__ __forceinline__ unsigned cloadu(const unsigned* p){
  return __hip_atomic_load(p, __ATOMIC_RELAXED, __HIP_MEMORY_SCOPE_AGENT);
}
__device__ __forceinline__ void cstoreu(unsigned* p, unsigned v){
  __hip_atomic_store(p, v, __ATOMIC_RELAXED, __HIP_MEMORY_SCOPE_AGENT);
}

// -------- prep: M1 = Wih@Wp, bias_e = Wih@bp + bih + bhh, dbias --------
__global__ __launch_bounds__(256) void prep_misc(
    const float* __restrict__ eWih, const float* __restrict__ Wp,
    const float* __restrict__ bp,  const float* __restrict__ ebih,
    const float* __restrict__ ebhh, const float* __restrict__ dbih,
    const float* __restrict__ dbhh,
    float* __restrict__ M1, float* __restrict__ bias_e, float* __restrict__ dbias)
{
  int c = blockIdx.x * 256 + threadIdx.x;
  const float* wr = eWih + (size_t)c * H;
  float m0 = 0.f, m1 = 0.f, mb = 0.f;
  for (int k = 0; k < H; k += 4){
    float4 w  = *(const float4*)(wr + k);
    float4 p0 = *(const float4*)(Wp + (size_t)k * 2);
    float4 p1 = *(const float4*)(Wp + (size_t)(k + 2) * 2);
    float4 bb = *(const float4*)(bp + k);
    m0 += w.x*p0.x + w.y*p0.z + w.z*p1.x + w.w*p1.z;
    m1 += w.x*p0.y + w.y*p0.w + w.z*p1.y + w.w*p1.w;
    mb += w.x*bb.x + w.y*bb.y + w.z*bb.z + w.w*bb.w;
  }
  M1[(size_t)c*2]   = m0;
  M1[(size_t)c*2+1] = m1;
  bias_e[c] = ebih[c] + ebhh[c] + mb;
  dbias[c]  = dbih[c] + dbhh[c];
}

// -------- E fill: E[b][t][c] = M1[c]·in[b,t] + bias_e[c] --------
__global__ __launch_bounds__(256) void efill(
    const float* __restrict__ inp, const float* __restrict__ M1,
    const float* __restrict__ be, float* __restrict__ E)
{
  size_t i = (size_t)blockIdx.x * 256 + threadIdx.x;
  int c = (int)(i & 2047);
  int t = (int)((i >> 11) & 127);
  int b = (int)(i >> 18);
  float x0 = inp[((size_t)b * S + t) * 2 + 0];
  float x1 = inp[((size_t)b * S + t) * 2 + 1];
  E[i] = M1[(size_t)c*2] * x0 + M1[(size_t)c*2+1] * x1 + be[c];
}

// -------- pack Whh into per-slice contiguous form WP[j][k][g*64+u] --------
__global__ __launch_bounds__(256) void pack_whh(
    const float* __restrict__ Whh, float* __restrict__ WP)
{
  size_t i = (size_t)blockIdx.x * 256 + threadIdx.x;
  int p = (int)(i & 255);
  int k = (int)((i >> 8) & 511);
  int j = (int)(i >> 17);
  int g = p >> 6, u = p & 63;
  int r = g * 512 + j * UPS + u;
  WP[i] = Whh[(size_t)r * H + k];
}

// -------- transpose: out[K][R] = in[R][K] --------
__global__ __launch_bounds__(256) void transpose_k(
    const float* __restrict__ in, float* __restrict__ out, int R, int K)
{
  __shared__ float tile[32][33];
  int r0 = blockIdx.y * 32, k0 = blockIdx.x * 32;
  int tx = threadIdx.x & 31, ty = threadIdx.x >> 5;
  #pragma unroll
  for (int j = 0; j < 4; ++j)
    tile[ty + 8*j][tx] = in[(size_t)(r0 + ty + 8*j) * K + k0 + tx];
  __syncthreads();
  #pragma unroll
  for (int j = 0; j < 4; ++j)
    out[(size_t)(k0 + ty + 8*j) * R + r0 + tx] = tile[tx][ty + 8*j];
}

// -------- generic fp32 GEMM: C = A(MxK) @ B(NxK)^T (+bias) --------
template<int LAYOUT>
__global__ __launch_bounds__(256) void gemm_nt(
    const float* __restrict__ A, const float* __restrict__ Bm,
    const float* __restrict__ bias, float* __restrict__ C,
    int M, int N, int K)
{
  __shared__ float As[16][68];
  __shared__ float Bs[16][68];
  int tid = threadIdx.x;
  int bm = blockIdx.y * 64, bn = blockIdx.x * 64;
  int tm = (tid & 15) * 4, tn = (tid >> 4) * 4;
  float acc[4][4] = {};
  int r  = tid >> 2;
  int kq = (tid & 3) * 4;
  for (int k0 = 0; k0 < K; k0 += 16){
    float4 a = *(const float4*)(A  + (size_t)(bm + r) * K + k0 + kq);
    float4 b = *(const float4*)(Bm + (size_t)(bn + r) * K + k0 + kq);
    __syncthreads();
    As[kq+0][r] = a.x; As[kq+1][r] = a.y; As[kq+2][r] = a.z; As[kq+3][r] = a.w;
    Bs[kq+0][r] = b.x; Bs[kq+1][r] = b.y; Bs[kq+2][r] = b.z; Bs[kq+3][r] = b.w;
    __syncthreads();
    #pragma unroll
    for (int kk = 0; kk < 16; ++kk){
      float4 av = *(const float4*)(&As[kk][tm]);
      float4 bv = *(const float4*)(&Bs[kk][tn]);
      acc[0][0] += av.x*bv.x; acc[0][1] += av.x*bv.y; acc[0][2] += av.x*bv.z; acc[0][3] += av.x*bv.w;
      acc[1][0] += av.y*bv.x; acc[1][1] += av.y*bv.y; acc[1][2] += av.y*bv.z; acc[1][3] += av.y*bv.w;
      acc[2][0] += av.z*bv.x; acc[2][1] += av.z*bv.y; acc[2][2] += av.z*bv.z; acc[2][3] += av.z*bv.w;
      acc[3][0] += av.w*bv.x; acc[3][1] += av.w*bv.y; acc[3][2] += av.w*bv.z; acc[3][3] += av.w*bv.w;
    }
  }
  #pragma unroll
  for (int i = 0; i < 4; ++i){
    int m = bm + tm + i;
    #pragma unroll
    for (int j = 0; j < 4; ++j){
      int n = bn + tn + j;
      float vv = acc[i][j] + (bias ? bias[n] : 0.f);
      if (LAYOUT == 0) C[(size_t)m * N + n] = vv;
      else             C[((size_t)(m >> 7) * 512 + n) * 128 + (m & 127)] = vv;
    }
  }
}

// gemv with 3-way weight source: regs (kk<KR), LDS (KR..KR+KL), L2 (rest)
__device__ __forceinline__ float4 gemv_split(
    const float4* wreg, const float* wlds, const float* wp,
    const float* hsh, int ph, int c4)
{
  float4 acc = {0.f, 0.f, 0.f, 0.f};
  #pragma unroll
  for (int kk = 0; kk < KR; ++kk){
    float hv = hsh[4*kk + ph];
    float4 w = wreg[kk];
    acc.x = fmaf(w.x, hv, acc.x); acc.y = fmaf(w.y, hv, acc.y);
    acc.z = fmaf(w.z, hv, acc.z); acc.w = fmaf(w.w, hv, acc.w);
  }
  #pragma unroll 4
  for (int kk = KR; kk < KR + KL; ++kk){
    float hv = hsh[4*kk + ph];
    float4 w = *(const float4*)&wlds[((4*kk + ph) - 4*KR) * RPS + c4*4];
    acc.x = fmaf(w.x, hv, acc.x); acc.y = fmaf(w.y, hv, acc.y);
    acc.z = fmaf(w.z, hv, acc.z); acc.w = fmaf(w.w, hv, acc.w);
  }
  const float* wq = wp + (size_t)(4*(KR+KL)) * RPS + ph * RPS + c4 * 4;
  #pragma unroll 4
  for (int kk = KR + KL; kk < 128; ++kk){
    float hv = hsh[4*kk + ph];
    float4 w = *(const float4*)(wq + (size_t)(kk - KR - KL) * 4 * RPS);
    acc.x = fmaf(w.x, hv, acc.x); acc.y = fmaf(w.y, hv, acc.y);
    acc.z = fmaf(w.z, hv, acc.z); acc.w = fmaf(w.w, hv, acc.w);
  }
  return acc;
}

// -------- encoder: grid=256, weight-cached gemv, batch-local XCD mapping ----
// bk = j*32 + b  =>  XCD(bk%8) = b%8: all 8 slices of batch b on one XCD.
__global__ __launch_bounds__(256) void encoder_kernel(
    const float* __restrict__ WP,     // [8][512][256]
    const float* __restrict__ E,      // [b][t][2048]
    float* __restrict__ hb,           // [B][2][H] (zeroed)
    float* __restrict__ c_buf,        // [B][H]
    float* __restrict__ enc_out,      // [b][t][h]
    unsigned* __restrict__ htags)     // 256 lines, (b*8+j)*32
{
  __shared__ float wlds[KL * 4 * RPS];   // 128KB
  __shared__ float hsh[H];
  __shared__ float gpart[4][RPS];
  __shared__ float gfin[4][UPS];
  __shared__ float hloc[UPS];
  const int tid = threadIdx.x, bk = blockIdx.x;
  const int b = bk & 31, j = bk >> 5;    // batch-local XCD mapping
  const int u0 = j * UPS;
  const float* wp = WP + (size_t)j * H * RPS;
  unsigned* myhtags = htags + (size_t)b * 8 * 32;
  const int ph = tid >> 6, c4 = tid & 63;
  for (int i = tid; i < KL * RPS; i += 256)
    *(float4*)&wlds[i*4] = *(const float4*)(wp + (size_t)(4*KR) * RPS + (size_t)i*4);
  float4 wreg[KR];
  #pragma unroll
  for (int kk = 0; kk < KR; ++kk)
    wreg[kk] = *(const float4*)(wp + (size_t)(4*kk + ph) * RPS + c4*4);
  float creg = 0.f;
  for (int t = 0; t < S; ++t){
    if (t > 0 && tid < 8){
      while (cloadu(myhtags + tid * 32) < (unsigned)t){}
    }
    __syncthreads();
    { float2 q = cload2(hb + ((size_t)b * 2 + ((t + 1) & 1)) * H + 2 * tid);
      hsh[2*tid] = q.x; hsh[2*tid + 1] = q.y; }
    __syncthreads();
    float4 acc = gemv_split(wreg, wlds, wp, hsh, ph, c4);
    *(float4*)&gpart[ph][c4 * 4] = acc;
    __syncthreads();
    if (tid < 64){
      float4 s0 = *(const float4*)&gpart[0][tid*4];
      float4 s1 = *(const float4*)&gpart[1][tid*4];
      float4 s2 = *(const float4*)&gpart[2][tid*4];
      float4 s3 = *(const float4*)&gpart[3][tid*4];
      int g = tid >> 4, uu = (tid & 15) * 4;
      float4 e = *(const float4*)(E + ((size_t)b * S + t) * G4 + g * 512 + u0 + uu);
      float4 s; s.x = s0.x+s1.x+s2.x+s3.x + e.x; s.y = s0.y+s1.y+s2.y+s3.y + e.y;
      s.z = s0.z+s1.z+s2.z+s3.z + e.z; s.w = s0.w+s1.w+s2.w+s3.w + e.w;
      *(float4*)&gfin[g][uu] = s;
    }
    __syncthreads();
    if (tid < UPS){
      float gi = gfin[0][tid], gf = gfin[1][tid], gg = gfin[2][tid], go = gfin[3][tid];
      creg = sigm(gf) * creg + sigm(gi) * tanh_(gg);
      hloc[tid] = sigm(go) * tanh_(creg);
    }
    __syncthreads();
    if (tid < 32){
      float h0 = hloc[2*tid], h1 = hloc[2*tid + 1];
      cstore2(hb + ((size_t)b * 2 + (t & 1)) * H + u0 + 2*tid, h0, h1);
      *(float2*)(enc_out + ((size_t)b * S + t) * H + u0 + 2*tid) = make_float2(h0, h1);
    }
    __syncthreads();   // drain publishes before tag
    if (tid == 0) cstoreu(myhtags + j * 32, (unsigned)(t + 1));
  }
  if (tid < UPS) c_buf[(size_t)b * H + u0 + tid] = creg;
}

// -------- decoder: fused y-blocks, grid=256, batch-local XCD mapping --------
// Structure and safety arguments identical to r14 (see r14 comments); only
// the bk->(b,j) mapping changed (b=bk&31, j=bk>>5) for XCD locality.
__global__ __launch_bounds__(256) void decoder_kernel(
    const float* __restrict__ WP,     // [8][512][256] packed dec Whh
    const float* __restrict__ D,      // [b][t][2048]
    const float* __restrict__ dbias,  // [2048]
    const float* __restrict__ W2T,    // [512][512]
    const float* __restrict__ Pt,     // [b][h][s]
    const float* __restrict__ vvec,   // [512]
    const float* __restrict__ c_buf,  // [B][H]
    const float* __restrict__ enc_out,// [b][t][h]
    float* __restrict__ hb,           // [B][2][H]
    float* __restrict__ psbuf,        // [B][2][8][128]
    unsigned* __restrict__ htags,     // 256 lines
    unsigned* __restrict__ pstags,    // 256 lines
    float* __restrict__ out)          // [b][t][s]
{
  __shared__ float wlds[KL * 4 * RPS];   // 128KB
  __shared__ float hsh[H];
  __shared__ float gpart[4][RPS];
  __shared__ float gfin[4][UPS];
  __shared__ float hloc[UPS];
  __shared__ float dps[4][UPS];
  __shared__ float dpl[UPS];
  __shared__ float vsh[UPS];
  __shared__ float pspart[2][128];
  __shared__ float wm[2]; __shared__ int wi[2]; __shared__ float wsum[2];
  const int tid = threadIdx.x, bk = blockIdx.x;
  const int b = bk & 31, j = bk >> 5;    // batch-local XCD mapping
  const int u0 = j * UPS;
  const float* wp = WP + (size_t)j * H * RPS;
  unsigned* myhtags  = htags  + (size_t)b * 8 * 32;
  unsigned* mypstags = pstags + (size_t)b * 8 * 32;
  const int ph = tid >> 6, c4 = tid & 63;
  for (int i = tid; i < KL * RPS; i += 256)
    *(float4*)&wlds[i*4] = *(const float4*)(wp + (size_t)(4*KR) * RPS + (size_t)i*4);
  float4 wreg[KR];
  #pragma unroll
  for (int kk = 0; kk < KR; ++kk)
    wreg[kk] = *(const float4*)(wp + (size_t)(4*kk + ph) * RPS + c4*4);
  float creg = (tid < UPS) ? c_buf[(size_t)b * H + u0 + tid] : 0.f;
  if (tid < UPS) vsh[tid] = vvec[u0 + tid];
  if (tid < 32){
    float2 hv = *(const float2*)(enc_out + ((size_t)b * S + (S-1)) * H + u0 + 2*tid);
    cstore2(hb + ((size_t)b * 2 + 1) * H + u0 + 2*tid, hv.x, hv.y);
  }
  __syncthreads();
  if (tid == 0) cstoreu(myhtags + j * 32, 1u);
  for (int t = 0; t < S; ++t){
    if (tid < 8){
      while (cloadu(myhtags + tid * 32) < (unsigned)(t + 1)) __builtin_amdgcn_s_sleep(1);
    }
    __syncthreads();
    { float2 q = cload2(hb + ((size_t)b * 2 + ((t + 1) & 1)) * H + 2 * tid);
      hsh[2*tid] = q.x; hsh[2*tid + 1] = q.y; }
    __syncthreads();
    if (t >= 1){
      {
        int nl = tid & 63, kq = tid >> 6;
        const float* w = W2T + (size_t)(kq * 128) * H + u0 + nl;
        float a = 0.f;
        #pragma unroll 8
        for (int k2 = 0; k2 < 128; ++k2)
          a = fmaf(w[(size_t)k2 * H], hsh[kq * 128 + k2], a);
        dps[kq][nl] = a;
      }
      __syncthreads();
      if (tid < UPS) dpl[tid] = dps[0][tid] + dps[1][tid] + dps[2][tid] + dps[3][tid];
      __syncthreads();
      {
        int s = tid & 127, nh = tid >> 7;
        const float* Pp = Pt + ((size_t)b * H + u0 + nh * 32) * S + s;
        float cs = 0.f;
        #pragma unroll 4
        for (int n = 0; n < 32; ++n){
          float x = Pp[(size_t)n * S] + dpl[nh * 32 + n];
          cs = fmaf(vsh[nh * 32 + n], tanh_(x), cs);
        }
        pspart[nh][s] = cs;
      }
      __syncthreads();
      if (tid < 64)
        cstore2(psbuf + (((size_t)b * 2 + ((t - 1) & 1)) * 8 + j) * 128 + 2 * tid,
                pspart[0][2*tid] + pspart[1][2*tid],
                pspart[0][2*tid+1] + pspart[1][2*tid+1]);
      __syncthreads();   // drain ps publish before tag
      if (tid == 0) cstoreu(mypstags + j * 32, (unsigned)t);
    }
    float4 acc = gemv_split(wreg, wlds, wp, hsh, ph, c4);
    *(float4*)&gpart[ph][c4 * 4] = acc;
    if (t >= 1 && tid < 8){
      while (cloadu(mypstags + tid * 32) < (unsigned)t) __builtin_amdgcn_s_sleep(1);
    }
    __syncthreads();
    float sc = 0.f;
    if (t >= 1 && tid < 128){
      const float* pp = psbuf + ((size_t)b * 2 + ((t - 1) & 1)) * 8 * 128 + tid;
      #pragma unroll
      for (int jj2 = 0; jj2 < 8; ++jj2) sc += cloadf(pp + jj2 * 128);
      float mv = sc; int mi = tid;
      #pragma unroll
      for (int off = 32; off > 0; off >>= 1){
        float ov = __shfl_xor(mv, off, 64);
        int   oi = __shfl_xor(mi, off, 64);
        if (ov > mv || (ov == mv && oi < mi)){ mv = ov; mi = oi; }
      }
      if ((tid & 63) == 0){ wm[tid >> 6] = mv; wi[tid >> 6] = mi; }
    }
    __syncthreads();
    int top = 0; float mglob = 0.f;
    if (t >= 1){
      if (wm[1] > wm[0] || (wm[1] == wm[0] && wi[1] < wi[0])){ top = wi[1]; mglob = wm[1]; }
      else { top = wi[0]; mglob = wm[0]; }
    }
    if (tid < 64){
      float4 s0 = *(const float4*)&gpart[0][tid*4];
      float4 s1 = *(const float4*)&gpart[1][tid*4];
      float4 s2 = *(const float4*)&gpart[2][tid*4];
      float4 s3 = *(const float4*)&gpart[3][tid*4];
      int g = tid >> 4, uu = (tid & 15) * 4;
      const float* xr = (t == 0) ? dbias : D + ((size_t)b * S + top) * G4;
      float4 e = *(const float4*)(xr + g * 512 + u0 + uu);
      float4 s; s.x = s0.x+s1.x+s2.x+s3.x + e.x; s.y = s0.y+s1.y+s2.y+s3.y + e.y;
      s.z = s0.z+s1.z+s2.z+s3.z + e.z; s.w = s0.w+s1.w+s2.w+s3.w + e.w;
      *(float4*)&gfin[g][uu] = s;
    }
    __syncthreads();
    if (tid < UPS){
      float gi = gfin[0][tid], gf = gfin[1][tid], gg = gfin[2][tid], go = gfin[3][tid];
      creg = sigm(gf) * creg + sigm(gi) * tanh_(gg);
      hloc[tid] = sigm(go) * tanh_(creg);
    }
    __syncthreads();
    if (tid < 32)
      cstore2(hb + ((size_t)b * 2 + (t & 1)) * H + u0 + 2*tid,
              hloc[2*tid], hloc[2*tid + 1]);
    __syncthreads();   // drain h publish before tag
    if (tid == 0) cstoreu(myhtags + j * 32, (unsigned)(t + 2));
    // rotating softmax duty (off the h critical path)
    if (t >= 1 && j == ((t - 1) & 7)){
      if (tid < 128){
        float ss = __expf(sc - mglob);
        #pragma unroll
        for (int off = 32; off > 0; off >>= 1) ss += __shfl_xor(ss, off, 64);
        if ((tid & 63) == 0) wsum[tid >> 6] = ss;
      }
      __syncthreads();
      if (tid < 128){
        float lse = __logf(wsum[0] + wsum[1]);
        out[((size_t)b * S + (t - 1)) * S + tid] = sc - mglob - lse;
      }
    }
  }
  // -------- epilogue: ps(127) + final softmax row 127 --------
  if (tid < 8){
    while (cloadu(myhtags + tid * 32) < (unsigned)(S + 1)) __builtin_amdgcn_s_sleep(1);
  }
  __syncthreads();
  { float2 q = cload2(hb + ((size_t)b * 2 + 1) * H + 2 * tid);
    hsh[2*tid] = q.x; hsh[2*tid + 1] = q.y; }
  __syncthreads();
  {
    int nl = tid & 63, kq = tid >> 6;
    const float* w = W2T + (size_t)(kq * 128) * H + u0 + nl;
    float a = 0.f;
    #pragma unroll 8
    for (int k2 = 0; k2 < 128; ++k2)
      a = fmaf(w[(size_t)k2 * H], hsh[kq * 128 + k2], a);
    dps[kq][nl] = a;
  }
  __syncthreads();
  if (tid < UPS) dpl[tid] = dps[0][tid] + dps[1][tid] + dps[2][tid] + dps[3][tid];
  __syncthreads();
  {
    int s = tid & 127, nh = tid >> 7;
    const float* Pp = Pt + ((size_t)b * H + u0 + nh * 32) * S + s;
    float cs = 0.f;
    #pragma unroll 4
    for (int n = 0; n < 32; ++n){
      float x = Pp[(size_t)n * S] + dpl[nh * 32 + n];
      cs = fmaf(vsh[nh * 32 + n], tanh_(x), cs);
    }
    pspart[nh][s] = cs;
  }
  __syncthreads();
  if (tid < 64)
    cstore2(psbuf + (((size_t)b * 2 + ((S - 1) & 1)) * 8 + j) * 128 + 2 * tid,
            pspart[0][2*tid] + pspart[1][2*tid],
            pspart[0][2*tid+1] + pspart[1][2*tid+1]);
  __syncthreads();
  if (tid == 0) cstoreu(mypstags + j * 32, (unsigned)S);
  if (j == 7){
    if (tid < 8){
      while (cloadu(mypstags + tid * 32) < (unsigned)S) __builtin_amdgcn_s_sleep(1);
    }
    __syncthreads();
    float sc = 0.f;
    if (tid < 128){
      const float* pp = psbuf + ((size_t)b * 2 + ((S - 1) & 1)) * 8 * 128 + tid;
      #pragma unroll
      for (int jj2 = 0; jj2 < 8; ++jj2) sc += cloadf(pp + jj2 * 128);
      float mv = sc;
      #pragma unroll
      for (int off = 32; off > 0; off >>= 1)
        mv = fmaxf(mv, __shfl_xor(mv, off, 64));
      if ((tid & 63) == 0) wm[tid >> 6] = mv;
    }
    __syncthreads();
    float mglob = fmaxf(wm[0], wm[1]);
    if (tid < 128){
      float ss = __expf(sc - mglob);
      #pragma unroll
      for (int off = 32; off > 0; off >>= 1) ss += __shfl_xor(ss, off, 64);
      if ((tid & 63) == 0) wsum[tid >> 6] = ss;
    }
    __syncthreads();
    if (tid < 128){
      float lse = __logf(wsum[0] + wsum[1]);
      out[((size_t)b * S + (S - 1)) * S + tid] = sc - mglob - lse;
    }
  }
}

extern "C" void kernel_launch(void* const* d_in, const int* in_sizes, int n_in,
                              void* d_out, int out_size, void* d_ws, size_t ws_size,
                              hipStream_t stream) {
  const float* inputs  = (const float*)d_in[0];
  const float* Wp      = (const float*)d_in[1];
  const float* bp      = (const float*)d_in[2];
  const float* eWih    = (const float*)d_in[3];
  const float* eWhh    = (const float*)d_in[4];
  const float* ebih    = (const float*)d_in[5];
  const float* ebhh    = (const float*)d_in[6];
  const float* dWih    = (const float*)d_in[7];
  const float* dWhh    = (const float*)d_in[8];
  const float* dbih    = (const float*)d_in[9];
  const float* dbhh    = (const float*)d_in[10];
  const float* W1      = (const float*)d_in[11];
  const float* W2      = (const float*)d_in[12];
  const float* v       = (const float*)d_in[13];
  float* out = (float*)d_out;

  float* ws = (float*)d_ws;
  float* E       = ws + OFF_E;    // reused as D after encoder
  float* enc_out = ws + OFF_EO;
  float* Pt      = ws + OFF_PT;
  float* WPe     = ws + OFF_WPE;
  float* WPd     = ws + OFF_WPD;
  float* W2T     = ws + OFF_W2T;
  float* hb      = ws + OFF_HB;
  float* c_buf   = ws + OFF_CB;
  float* psbuf   = ws + OFF_PS;
  float* M1      = ws + OFF_M1;
  float* bias_e  = ws + OFF_BE;
  float* dbias   = ws + OFF_DB;
  unsigned* enc_htags = (unsigned*)(ws + OFF_END);
  unsigned* dec_htags = enc_htags + 256 * 32;
  unsigned* pstags    = dec_htags + 256 * 32;

  hipMemsetAsync(hb, 0, (size_t)B * 2 * H * sizeof(float), stream);
  hipMemsetAsync(enc_htags, 0, CTRL_U32 * sizeof(unsigned), stream);

  prep_misc<<<G4 / 256, 256, 0, stream>>>(eWih, Wp, bp, ebih, ebhh, dbih, dbhh,
                                          M1, bias_e, dbias);
  efill<<<(int)(SZ_E / 256), 256, 0, stream>>>(inputs, M1, bias_e, E);
  pack_whh<<<(int)(SZ_WP / 256), 256, 0, stream>>>(eWhh, WPe);
  pack_whh<<<(int)(SZ_WP / 256), 256, 0, stream>>>(dWhh, WPd);
  { dim3 g(H / 32, H / 32); transpose_k<<<g, 256, 0, stream>>>(W2, W2T, H, H); }

  encoder_kernel<<<256, 256, 0, stream>>>(WPe, E, hb, c_buf, enc_out, enc_htags);

  float* D = E;
  { dim3 grid(G4 / 64, (B * S) / 64);
    gemm_nt<0><<<grid, 256, 0, stream>>>(enc_out, dWih, dbias, D, B * S, G4, H); }
  { dim3 grid(H / 64, (B * S) / 64);
    gemm_nt<1><<<grid, 256, 0, stream>>>(enc_out, W1, nullptr, Pt, B * S, H, H); }

  decoder_kernel<<<256, 256, 0, stream>>>(WPd, D, dbias, W2T, Pt, v, c_buf,
                                          enc_out, hb, psbuf,
                                          dec_htags, pstags, out);
  (void)in_sizes; (void)n_in; (void)out_size; (void)ws_size;
}

// Round 18
// 2418.500 us; speedup vs baseline: 1.9638x; 1.2090x over previous
//
#include <hip/hip_runtime.h>
#include <math.h>

// Problem constants
static constexpr int H   = 512;
static constexpr int B   = 32;
static constexpr int S   = 128;
static constexpr int G4  = 2048;  // 4*H
static constexpr int UPS = 64;    // units per y-slice
static constexpr int RPS = 256;   // rows per y-slice (4 gates * UPS)
static constexpr int NSL = 8;     // y-slices per batch

// ws layout (floats)
static constexpr size_t OFF_E   = 0;                          // E [b][t][c]; reused as D
static constexpr size_t SZ_E    = (size_t)B * S * G4;
static constexpr size_t OFF_EO  = OFF_E + SZ_E;               // enc_out [b][t][h]
static constexpr size_t SZ_EO   = (size_t)B * S * H;
static constexpr size_t OFF_PT  = OFF_EO + SZ_EO;             // P_t [b][h][s]
static constexpr size_t SZ_PT   = (size_t)B * H * S;
static constexpr size_t OFF_WPE = OFF_PT + SZ_PT;             // packed enc Whh [8][512][256]
static constexpr size_t SZ_WP   = (size_t)NSL * H * RPS;
static constexpr size_t OFF_WPD = OFF_WPE + SZ_WP;            // packed dec Whh
static constexpr size_t OFF_W2T = OFF_WPD + SZ_WP;            // W2T [512][512]
static constexpr size_t OFF_HB  = OFF_W2T + (size_t)H * H;    // hb [B][2][H]
static constexpr size_t OFF_CB  = OFF_HB + (size_t)B * 2 * H; // c_buf [B][H]
static constexpr size_t OFF_PS  = OFF_CB + (size_t)B * H;     // psbuf [B][2][8][128]
static constexpr size_t SZ_PS   = (size_t)B * 2 * 8 * 128;
static constexpr size_t OFF_M1  = OFF_PS + SZ_PS;
static constexpr size_t OFF_BE  = OFF_M1 + (size_t)G4 * 2;
static constexpr size_t OFF_DB  = OFF_BE + G4;
static constexpr size_t OFF_END = OFF_DB + G4;
// u32 ctrl: enc_htags[256], dec_htags[256], pstags[256] (x32-u32 lines)
static constexpr int CTRL_U32 = (256 + 256 + 256) * 32;

// weight-cache split (kk = k-quad index, 128 total). KR=32 proven no-spill
// (VGPR=132). KR=64 spills at the 168-VGPR cap regardless of launch_bounds
// (r15/r16). Mapping bk=b*8+j is XCD-slice-local: slice j L2-resident on
// XCD j (r17: batch-local mapping thrashes L2, FETCH x3).
static constexpr int KR = 32;   // kk 0..31  -> registers (k-rows 0..127)
static constexpr int KL = 32;   // kk 32..63 -> LDS (k-rows 128..255, 128KB)
// kk 64..127 -> streamed from L2 (k-rows 256..511, 256KB)

__device__ __forceinline__ float sigm(float x){
  float e = __expf(-x);
  return 1.0f / (1.0f + e);
}
__device__ __forceinline__ float tanh_(float x){
  float e = __expf(2.0f * x);
  return 1.0f - 2.0f / (1.0f + e);
}

// agent-scope (coherence-point) accessors; discipline: __syncthreads (vmcnt
// drain) between data stores and the tag store (validated r2-r17)
__device__ __forceinline__ float cloadf(const float* p){
  union { unsigned u; float f; } c;
  c.u = __hip_atomic_load((const unsigned*)p, __ATOMIC_RELAXED,
                          __HIP_MEMORY_SCOPE_AGENT);
  return c.f;
}
__device__ __forceinline__ float2 cload2(const float* p){
  union { unsigned long long u; float2 f; } c;
  c.u = __hip_atomic_load((const unsigned long long*)p, __ATOMIC_RELAXED,
                          __HIP_MEMORY_SCOPE_AGENT);
  return c.f;
}
__device__ __forceinline__ void cstore2(float* p, float a, float b){
  union { unsigned long long u; float2 f; } c;
  c.f = make_float2(a, b);
  __hip_atomic_store((unsigned long long*)p, c.u, __ATOMIC_RELAXED,
                     __HIP_MEMORY_SCOPE_AGENT);
}
__device__ __forceinline__ unsigned cloadu(const unsigned* p){
  return __hip_atomic_load(p, __ATOMIC_RELAXED, __HIP_MEMORY_SCOPE_AGENT);
}
__device__ __forceinline__ void cstoreu(unsigned* p, unsigned v){
  __hip_atomic_store(p, v, __ATOMIC_RELAXED, __HIP_MEMORY_SCOPE_AGENT);
}

// -------- prep: M1 = Wih@Wp, bias_e = Wih@bp + bih + bhh, dbias --------
__global__ __launch_bounds__(256) void prep_misc(
    const float* __restrict__ eWih, const float* __restrict__ Wp,
    const float* __restrict__ bp,  const float* __restrict__ ebih,
    const float* __restrict__ ebhh, const float* __restrict__ dbih,
    const float* __restrict__ dbhh,
    float* __restrict__ M1, float* __restrict__ bias_e, float* __restrict__ dbias)
{
  int c = blockIdx.x * 256 + threadIdx.x;
  const float* wr = eWih + (size_t)c * H;
  float m0 = 0.f, m1 = 0.f, mb = 0.f;
  for (int k = 0; k < H; k += 4){
    float4 w  = *(const float4*)(wr + k);
    float4 p0 = *(const float4*)(Wp + (size_t)k * 2);
    float4 p1 = *(const float4*)(Wp + (size_t)(k + 2) * 2);
    float4 bb = *(const float4*)(bp + k);
    m0 += w.x*p0.x + w.y*p0.z + w.z*p1.x + w.w*p1.z;
    m1 += w.x*p0.y + w.y*p0.w + w.z*p1.y + w.w*p1.w;
    mb += w.x*bb.x + w.y*bb.y + w.z*bb.z + w.w*bb.w;
  }
  M1[(size_t)c*2]   = m0;
  M1[(size_t)c*2+1] = m1;
  bias_e[c] = ebih[c] + ebhh[c] + mb;
  dbias[c]  = dbih[c] + dbhh[c];
}

// -------- E fill: E[b][t][c] = M1[c]·in[b,t] + bias_e[c] --------
__global__ __launch_bounds__(256) void efill(
    const float* __restrict__ inp, const float* __restrict__ M1,
    const float* __restrict__ be, float* __restrict__ E)
{
  size_t i = (size_t)blockIdx.x * 256 + threadIdx.x;
  int c = (int)(i & 2047);
  int t = (int)((i >> 11) & 127);
  int b = (int)(i >> 18);
  float x0 = inp[((size_t)b * S + t) * 2 + 0];
  float x1 = inp[((size_t)b * S + t) * 2 + 1];
  E[i] = M1[(size_t)c*2] * x0 + M1[(size_t)c*2+1] * x1 + be[c];
}

// -------- pack Whh into per-slice contiguous form WP[j][k][g*64+u] --------
__global__ __launch_bounds__(256) void pack_whh(
    const float* __restrict__ Whh, float* __restrict__ WP)
{
  size_t i = (size_t)blockIdx.x * 256 + threadIdx.x;
  int p = (int)(i & 255);
  int k = (int)((i >> 8) & 511);
  int j = (int)(i >> 17);
  int g = p >> 6, u = p & 63;
  int r = g * 512 + j * UPS + u;
  WP[i] = Whh[(size_t)r * H + k];
}

// -------- transpose: out[K][R] = in[R][K] --------
__global__ __launch_bounds__(256) void transpose_k(
    const float* __restrict__ in, float* __restrict__ out, int R, int K)
{
  __shared__ float tile[32][33];
  int r0 = blockIdx.y * 32, k0 = blockIdx.x * 32;
  int tx = threadIdx.x & 31, ty = threadIdx.x >> 5;
  #pragma unroll
  for (int j = 0; j < 4; ++j)
    tile[ty + 8*j][tx] = in[(size_t)(r0 + ty + 8*j) * K + k0 + tx];
  __syncthreads();
  #pragma unroll
  for (int j = 0; j < 4; ++j)
    out[(size_t)(k0 + ty + 8*j) * R + r0 + tx] = tile[tx][ty + 8*j];
}

// -------- generic fp32 GEMM: C = A(MxK) @ B(NxK)^T (+bias) --------
template<int LAYOUT>
__global__ __launch_bounds__(256) void gemm_nt(
    const float* __restrict__ A, const float* __restrict__ Bm,
    const float* __restrict__ bias, float* __restrict__ C,
    int M, int N, int K)
{
  __shared__ float As[16][68];
  __shared__ float Bs[16][68];
  int tid = threadIdx.x;
  int bm = blockIdx.y * 64, bn = blockIdx.x * 64;
  int tm = (tid & 15) * 4, tn = (tid >> 4) * 4;
  float acc[4][4] = {};
  int r  = tid >> 2;
  int kq = (tid & 3) * 4;
  for (int k0 = 0; k0 < K; k0 += 16){
    float4 a = *(const float4*)(A  + (size_t)(bm + r) * K + k0 + kq);
    float4 b = *(const float4*)(Bm + (size_t)(bn + r) * K + k0 + kq);
    __syncthreads();
    As[kq+0][r] = a.x; As[kq+1][r] = a.y; As[kq+2][r] = a.z; As[kq+3][r] = a.w;
    Bs[kq+0][r] = b.x; Bs[kq+1][r] = b.y; Bs[kq+2][r] = b.z; Bs[kq+3][r] = b.w;
    __syncthreads();
    #pragma unroll
    for (int kk = 0; kk < 16; ++kk){
      float4 av = *(const float4*)(&As[kk][tm]);
      float4 bv = *(const float4*)(&Bs[kk][tn]);
      acc[0][0] += av.x*bv.x; acc[0][1] += av.x*bv.y; acc[0][2] += av.x*bv.z; acc[0][3] += av.x*bv.w;
      acc[1][0] += av.y*bv.x; acc[1][1] += av.y*bv.y; acc[1][2] += av.y*bv.z; acc[1][3] += av.y*bv.w;
      acc[2][0] += av.z*bv.x; acc[2][1] += av.z*bv.y; acc[2][2] += av.z*bv.z; acc[2][3] += av.z*bv.w;
      acc[3][0] += av.w*bv.x; acc[3][1] += av.w*bv.y; acc[3][2] += av.w*bv.z; acc[3][3] += av.w*bv.w;
    }
  }
  #pragma unroll
  for (int i = 0; i < 4; ++i){
    int m = bm + tm + i;
    #pragma unroll
    for (int j = 0; j < 4; ++j){
      int n = bn + tn + j;
      float vv = acc[i][j] + (bias ? bias[n] : 0.f);
      if (LAYOUT == 0) C[(size_t)m * N + n] = vv;
      else             C[((size_t)(m >> 7) * 512 + n) * 128 + (m & 127)] = vv;
    }
  }
}

// gemv with 3-way weight source: regs (kk<KR), LDS (KR..KR+KL), L2 (rest)
__device__ __forceinline__ float4 gemv_split(
    const float4* wreg, const float* wlds, const float* wp,
    const float* hsh, int ph, int c4)
{
  float4 acc = {0.f, 0.f, 0.f, 0.f};
  #pragma unroll
  for (int kk = 0; kk < KR; ++kk){
    float hv = hsh[4*kk + ph];
    float4 w = wreg[kk];
    acc.x = fmaf(w.x, hv, acc.x); acc.y = fmaf(w.y, hv, acc.y);
    acc.z = fmaf(w.z, hv, acc.z); acc.w = fmaf(w.w, hv, acc.w);
  }
  #pragma unroll 4
  for (int kk = KR; kk < KR + KL; ++kk){
    float hv = hsh[4*kk + ph];
    float4 w = *(const float4*)&wlds[((4*kk + ph) - 4*KR) * RPS + c4*4];
    acc.x = fmaf(w.x, hv, acc.x); acc.y = fmaf(w.y, hv, acc.y);
    acc.z = fmaf(w.z, hv, acc.z); acc.w = fmaf(w.w, hv, acc.w);
  }
  const float* wq = wp + (size_t)(4*(KR+KL)) * RPS + ph * RPS + c4 * 4;
  #pragma unroll 4
  for (int kk = KR + KL; kk < 128; ++kk){
    float hv = hsh[4*kk + ph];
    float4 w = *(const float4*)(wq + (size_t)(kk - KR - KL) * 4 * RPS);
    acc.x = fmaf(w.x, hv, acc.x); acc.y = fmaf(w.y, hv, acc.y);
    acc.z = fmaf(w.z, hv, acc.z); acc.w = fmaf(w.w, hv, acc.w);
  }
  return acc;
}

// -------- encoder: grid=256, weight-cached gemv --------
__global__ __launch_bounds__(256) void encoder_kernel(
    const float* __restrict__ WP,     // [8][512][256]
    const float* __restrict__ E,      // [b][t][2048]
    float* __restrict__ hb,           // [B][2][H] (zeroed)
    float* __restrict__ c_buf,        // [B][H]
    float* __restrict__ enc_out,      // [b][t][h]
    unsigned* __restrict__ htags)     // 256 lines, (b*8+j)*32
{
  __shared__ float wlds[KL * 4 * RPS];   // 128KB
  __shared__ float hsh[H];
  __shared__ float gpart[4][RPS];
  __shared__ float gfin[4][UPS];
  __shared__ float hloc[UPS];
  const int tid = threadIdx.x, bk = blockIdx.x;
  const int b = bk >> 3, j = bk & 7;     // slice-local XCD mapping (XCD=j)
  const int u0 = j * UPS;
  const float* wp = WP + (size_t)j * H * RPS;
  unsigned* myhtags = htags + (size_t)b * 8 * 32;
  const int ph = tid >> 6, c4 = tid & 63;
  for (int i = tid; i < KL * RPS; i += 256)
    *(float4*)&wlds[i*4] = *(const float4*)(wp + (size_t)(4*KR) * RPS + (size_t)i*4);
  float4 wreg[KR];
  #pragma unroll
  for (int kk = 0; kk < KR; ++kk)
    wreg[kk] = *(const float4*)(wp + (size_t)(4*kk + ph) * RPS + c4*4);
  float creg = 0.f;
  for (int t = 0; t < S; ++t){
    if (t > 0 && tid < 8){
      while (cloadu(myhtags + tid * 32) < (unsigned)t){}
    }
    __syncthreads();
    { float2 q = cload2(hb + ((size_t)b * 2 + ((t + 1) & 1)) * H + 2 * tid);
      hsh[2*tid] = q.x; hsh[2*tid + 1] = q.y; }
    __syncthreads();
    float4 acc = gemv_split(wreg, wlds, wp, hsh, ph, c4);
    *(float4*)&gpart[ph][c4 * 4] = acc;
    __syncthreads();
    if (tid < 64){
      float4 s0 = *(const float4*)&gpart[0][tid*4];
      float4 s1 = *(const float4*)&gpart[1][tid*4];
      float4 s2 = *(const float4*)&gpart[2][tid*4];
      float4 s3 = *(const float4*)&gpart[3][tid*4];
      int g = tid >> 4, uu = (tid & 15) * 4;
      float4 e = *(const float4*)(E + ((size_t)b * S + t) * G4 + g * 512 + u0 + uu);
      float4 s; s.x = s0.x+s1.x+s2.x+s3.x + e.x; s.y = s0.y+s1.y+s2.y+s3.y + e.y;
      s.z = s0.z+s1.z+s2.z+s3.z + e.z; s.w = s0.w+s1.w+s2.w+s3.w + e.w;
      *(float4*)&gfin[g][uu] = s;
    }
    __syncthreads();
    if (tid < UPS){
      float gi = gfin[0][tid], gf = gfin[1][tid], gg = gfin[2][tid], go = gfin[3][tid];
      creg = sigm(gf) * creg + sigm(gi) * tanh_(gg);
      hloc[tid] = sigm(go) * tanh_(creg);
    }
    __syncthreads();
    if (tid < 32){
      float h0 = hloc[2*tid], h1 = hloc[2*tid + 1];
      cstore2(hb + ((size_t)b * 2 + (t & 1)) * H + u0 + 2*tid, h0, h1);
      *(float2*)(enc_out + ((size_t)b * S + t) * H + u0 + 2*tid) = make_float2(h0, h1);
    }
    __syncthreads();   // drain publishes before tag
    if (tid == 0) cstoreu(myhtags + j * 32, (unsigned)(t + 1));
  }
  if (tid < UPS) c_buf[(size_t)b * H + u0 + tid] = creg;
}

// -------- decoder: fused y-blocks only, grid=256, weight-cached gemv --------
// htag[b*8+j] = t+2 <=> h(t) slice j published (parity t&1); init 1 <=> h(-1)
//   at parity 1 (= enc h(127)).
// Step t: poll 8 htags>=t+1; stage h(t-1) [(t+1)&1]; t>=1: dp-slice (own 64
//   units), ps(t-1)-partial, publish psbuf[b][(t-1)&1][j], pstag=t; gemv
//   (reg/LDS/L2 split); poll 8 pstags>=t; sum partials + argmax -> top(t-1)
//   (+max value); x-term; pointwise; publish h(t); htag=t+2; then the block
//   with j==(t-1)&7 does softmax + out row t-1 (off the h critical path).
// Epilogue: ps(127) publish (pstag=S); j==7 polls pstags>=S, softmax row 127.
// psbuf safety (double-buffered): writer of ps(t) parity t&1 at step t+1 is
//   gated by htags>=t+2 => every block completed step t; prior parity
//   occupant ps(t-2) read by argmax at step t-1 and softmax of row t-2 at
//   end of step t-1 (precedes that block's step-t h-publish) => done.
// hb ping-pong safety: htags>=t+1 => all staged h(t-1) => done with h(t-2).
__global__ __launch_bounds__(256) void decoder_kernel(
    const float* __restrict__ WP,     // [8][512][256] packed dec Whh
    const float* __restrict__ D,      // [b][t][2048]
    const float* __restrict__ dbias,  // [2048]
    const float* __restrict__ W2T,    // [512][512]
    const float* __restrict__ Pt,     // [b][h][s]
    const float* __restrict__ vvec,   // [512]
    const float* __restrict__ c_buf,  // [B][H]
    const float* __restrict__ enc_out,// [b][t][h]
    float* __restrict__ hb,           // [B][2][H]
    float* __restrict__ psbuf,        // [B][2][8][128]
    unsigned* __restrict__ htags,     // 256 lines
    unsigned* __restrict__ pstags,    // 256 lines
    float* __restrict__ out)          // [b][t][s]
{
  __shared__ float wlds[KL * 4 * RPS];   // 128KB
  __shared__ float hsh[H];
  __shared__ float gpart[4][RPS];
  __shared__ float gfin[4][UPS];
  __shared__ float hloc[UPS];
  __shared__ float dps[4][UPS];
  __shared__ float dpl[UPS];
  __shared__ float vsh[UPS];
  __shared__ float pspart[2][128];
  __shared__ float wm[2]; __shared__ int wi[2]; __shared__ float wsum[2];
  const int tid = threadIdx.x, bk = blockIdx.x;
  const int b = bk >> 3, j = bk & 7;     // slice-local XCD mapping (XCD=j)
  const int u0 = j * UPS;
  const float* wp = WP + (size_t)j * H * RPS;
  unsigned* myhtags  = htags  + (size_t)b * 8 * 32;
  unsigned* mypstags = pstags + (size_t)b * 8 * 32;
  const int ph = tid >> 6, c4 = tid & 63;
  for (int i = tid; i < KL * RPS; i += 256)
    *(float4*)&wlds[i*4] = *(const float4*)(wp + (size_t)(4*KR) * RPS + (size_t)i*4);
  float4 wreg[KR];
  #pragma unroll
  for (int kk = 0; kk < KR; ++kk)
    wreg[kk] = *(const float4*)(wp + (size_t)(4*kk + ph) * RPS + c4*4);
  float creg = (tid < UPS) ? c_buf[(size_t)b * H + u0 + tid] : 0.f;
  if (tid < UPS) vsh[tid] = vvec[u0 + tid];
  if (tid < 32){
    float2 hv = *(const float2*)(enc_out + ((size_t)b * S + (S-1)) * H + u0 + 2*tid);
    cstore2(hb + ((size_t)b * 2 + 1) * H + u0 + 2*tid, hv.x, hv.y);
  }
  __syncthreads();
  if (tid == 0) cstoreu(myhtags + j * 32, 1u);
  for (int t = 0; t < S; ++t){
    if (tid < 8){
      while (cloadu(myhtags + tid * 32) < (unsigned)(t + 1)) __builtin_amdgcn_s_sleep(1);
    }
    __syncthreads();
    { float2 q = cload2(hb + ((size_t)b * 2 + ((t + 1) & 1)) * H + 2 * tid);
      hsh[2*tid] = q.x; hsh[2*tid + 1] = q.y; }
    __syncthreads();
    if (t >= 1){
      {
        int nl = tid & 63, kq = tid >> 6;
        const float* w = W2T + (size_t)(kq * 128) * H + u0 + nl;
        float a = 0.f;
        #pragma unroll 8
        for (int k2 = 0; k2 < 128; ++k2)
          a = fmaf(w[(size_t)k2 * H], hsh[kq * 128 + k2], a);
        dps[kq][nl] = a;
      }
      __syncthreads();
      if (tid < UPS) dpl[tid] = dps[0][tid] + dps[1][tid] + dps[2][tid] + dps[3][tid];
      __syncthreads();
      {
        int s = tid & 127, nh = tid >> 7;
        const float* Pp = Pt + ((size_t)b * H + u0 + nh * 32) * S + s;
        float cs = 0.f;
        #pragma unroll 4
        for (int n = 0; n < 32; ++n){
          float x = Pp[(size_t)n * S] + dpl[nh * 32 + n];
          cs = fmaf(vsh[nh * 32 + n], tanh_(x), cs);
        }
        pspart[nh][s] = cs;
      }
      __syncthreads();
      if (tid < 64)
        cstore2(psbuf + (((size_t)b * 2 + ((t - 1) & 1)) * 8 + j) * 128 + 2 * tid,
                pspart[0][2*tid] + pspart[1][2*tid],
                pspart[0][2*tid+1] + pspart[1][2*tid+1]);
      __syncthreads();   // drain ps publish before tag
      if (tid == 0) cstoreu(mypstags + j * 32, (unsigned)t);
    }
    float4 acc = gemv_split(wreg, wlds, wp, hsh, ph, c4);
    *(float4*)&gpart[ph][c4 * 4] = acc;
    if (t >= 1 && tid < 8){
      while (cloadu(mypstags + tid * 32) < (unsigned)t) __builtin_amdgcn_s_sleep(1);
    }
    __syncthreads();
    float sc = 0.f;
    if (t >= 1 && tid < 128){
      const float* pp = psbuf + ((size_t)b * 2 + ((t - 1) & 1)) * 8 * 128 + tid;
      #pragma unroll
      for (int jj2 = 0; jj2 < 8; ++jj2) sc += cloadf(pp + jj2 * 128);
      float mv = sc; int mi = tid;
      #pragma unroll
      for (int off = 32; off > 0; off >>= 1){
        float ov = __shfl_xor(mv, off, 64);
        int   oi = __shfl_xor(mi, off, 64);
        if (ov > mv || (ov == mv && oi < mi)){ mv = ov; mi = oi; }
      }
      if ((tid & 63) == 0){ wm[tid >> 6] = mv; wi[tid >> 6] = mi; }
    }
    __syncthreads();
    int top = 0; float mglob = 0.f;
    if (t >= 1){
      if (wm[1] > wm[0] || (wm[1] == wm[0] && wi[1] < wi[0])){ top = wi[1]; mglob = wm[1]; }
      else { top = wi[0]; mglob = wm[0]; }
    }
    if (tid < 64){
      float4 s0 = *(const float4*)&gpart[0][tid*4];
      float4 s1 = *(const float4*)&gpart[1][tid*4];
      float4 s2 = *(const float4*)&gpart[2][tid*4];
      float4 s3 = *(const float4*)&gpart[3][tid*4];
      int g = tid >> 4, uu = (tid & 15) * 4;
      const float* xr = (t == 0) ? dbias : D + ((size_t)b * S + top) * G4;
      float4 e = *(const float4*)(xr + g * 512 + u0 + uu);
      float4 s; s.x = s0.x+s1.x+s2.x+s3.x + e.x; s.y = s0.y+s1.y+s2.y+s3.y + e.y;
      s.z = s0.z+s1.z+s2.z+s3.z + e.z; s.w = s0.w+s1.w+s2.w+s3.w + e.w;
      *(float4*)&gfin[g][uu] = s;
    }
    __syncthreads();
    if (tid < UPS){
      float gi = gfin[0][tid], gf = gfin[1][tid], gg = gfin[2][tid], go = gfin[3][tid];
      creg = sigm(gf) * creg + sigm(gi) * tanh_(gg);
      hloc[tid] = sigm(go) * tanh_(creg);
    }
    __syncthreads();
    if (tid < 32)
      cstore2(hb + ((size_t)b * 2 + (t & 1)) * H + u0 + 2*tid,
              hloc[2*tid], hloc[2*tid + 1]);
    __syncthreads();   // drain h publish before tag
    if (tid == 0) cstoreu(myhtags + j * 32, (unsigned)(t + 2));
    // rotating softmax duty (off the h critical path)
    if (t >= 1 && j == ((t - 1) & 7)){
      if (tid < 128){
        float ss = __expf(sc - mglob);
        #pragma unroll
        for (int off = 32; off > 0; off >>= 1) ss += __shfl_xor(ss, off, 64);
        if ((tid & 63) == 0) wsum[tid >> 6] = ss;
      }
      __syncthreads();
      if (tid < 128){
        float lse = __logf(wsum[0] + wsum[1]);
        out[((size_t)b * S + (t - 1)) * S + tid] = sc - mglob - lse;
      }
    }
  }
  // -------- epilogue: ps(127) + final softmax row 127 --------
  if (tid < 8){
    while (cloadu(myhtags + tid * 32) < (unsigned)(S + 1)) __builtin_amdgcn_s_sleep(1);
  }
  __syncthreads();
  { float2 q = cload2(hb + ((size_t)b * 2 + 1) * H + 2 * tid);
    hsh[2*tid] = q.x; hsh[2*tid + 1] = q.y; }
  __syncthreads();
  {
    int nl = tid & 63, kq = tid >> 6;
    const float* w = W2T + (size_t)(kq * 128) * H + u0 + nl;
    float a = 0.f;
    #pragma unroll 8
    for (int k2 = 0; k2 < 128; ++k2)
      a = fmaf(w[(size_t)k2 * H], hsh[kq * 128 + k2], a);
    dps[kq][nl] = a;
  }
  __syncthreads();
  if (tid < UPS) dpl[tid] = dps[0][tid] + dps[1][tid] + dps[2][tid] + dps[3][tid];
  __syncthreads();
  {
    int s = tid & 127, nh = tid >> 7;
    const float* Pp = Pt + ((size_t)b * H + u0 + nh * 32) * S + s;
    float cs = 0.f;
    #pragma unroll 4
    for (int n = 0; n < 32; ++n){
      float x = Pp[(size_t)n * S] + dpl[nh * 32 + n];
      cs = fmaf(vsh[nh * 32 + n], tanh_(x), cs);
    }
    pspart[nh][s] = cs;
  }
  __syncthreads();
  if (tid < 64)
    cstore2(psbuf + (((size_t)b * 2 + ((S - 1) & 1)) * 8 + j) * 128 + 2 * tid,
            pspart[0][2*tid] + pspart[1][2*tid],
            pspart[0][2*tid+1] + pspart[1][2*tid+1]);
  __syncthreads();
  if (tid == 0) cstoreu(mypstags + j * 32, (unsigned)S);
  if (j == 7){
    if (tid < 8){
      while (cloadu(mypstags + tid * 32) < (unsigned)S) __builtin_amdgcn_s_sleep(1);
    }
    __syncthreads();
    float sc = 0.f;
    if (tid < 128){
      const float* pp = psbuf + ((size_t)b * 2 + ((S - 1) & 1)) * 8 * 128 + tid;
      #pragma unroll
      for (int jj2 = 0; jj2 < 8; ++jj2) sc += cloadf(pp + jj2 * 128);
      float mv = sc;
      #pragma unroll
      for (int off = 32; off > 0; off >>= 1)
        mv = fmaxf(mv, __shfl_xor(mv, off, 64));
      if ((tid & 63) == 0) wm[tid >> 6] = mv;
    }
    __syncthreads();
    float mglob = fmaxf(wm[0], wm[1]);
    if (tid < 128){
      float ss = __expf(sc - mglob);
      #pragma unroll
      for (int off = 32; off > 0; off >>= 1) ss += __shfl_xor(ss, off, 64);
      if ((tid & 63) == 0) wsum[tid >> 6] = ss;
    }
    __syncthreads();
    if (tid < 128){
      float lse = __logf(wsum[0] + wsum[1]);
      out[((size_t)b * S + (S - 1)) * S + tid] = sc - mglob - lse;
    }
  }
}

extern "C" void kernel_launch(void* const* d_in, const int* in_sizes, int n_in,
                              void* d_out, int out_size, void* d_ws, size_t ws_size,
                              hipStream_t stream) {
  const float* inputs  = (const float*)d_in[0];
  const float* Wp      = (const float*)d_in[1];
  const float* bp      = (const float*)d_in[2];
  const float* eWih    = (const float*)d_in[3];
  const float* eWhh    = (const float*)d_in[4];
  const float* ebih    = (const float*)d_in[5];
  const float* ebhh    = (const float*)d_in[6];
  const float* dWih    = (const float*)d_in[7];
  const float* dWhh    = (const float*)d_in[8];
  const float* dbih    = (const float*)d_in[9];
  const float* dbhh    = (const float*)d_in[10];
  const float* W1      = (const float*)d_in[11];
  const float* W2      = (const float*)d_in[12];
  const float* v       = (const float*)d_in[13];
  float* out = (float*)d_out;

  float* ws = (float*)d_ws;
  float* E       = ws + OFF_E;    // reused as D after encoder
  float* enc_out = ws + OFF_EO;
  float* Pt      = ws + OFF_PT;
  float* WPe     = ws + OFF_WPE;
  float* WPd     = ws + OFF_WPD;
  float* W2T     = ws + OFF_W2T;
  float* hb      = ws + OFF_HB;
  float* c_buf   = ws + OFF_CB;
  float* psbuf   = ws + OFF_PS;
  float* M1      = ws + OFF_M1;
  float* bias_e  = ws + OFF_BE;
  float* dbias   = ws + OFF_DB;
  unsigned* enc_htags = (unsigned*)(ws + OFF_END);
  unsigned* dec_htags = enc_htags + 256 * 32;
  unsigned* pstags    = dec_htags + 256 * 32;

  hipMemsetAsync(hb, 0, (size_t)B * 2 * H * sizeof(float), stream);
  hipMemsetAsync(enc_htags, 0, CTRL_U32 * sizeof(unsigned), stream);

  prep_misc<<<G4 / 256, 256, 0, stream>>>(eWih, Wp, bp, ebih, ebhh, dbih, dbhh,
                                          M1, bias_e, dbias);
  efill<<<(int)(SZ_E / 256), 256, 0, stream>>>(inputs, M1, bias_e, E);
  pack_whh<<<(int)(SZ_WP / 256), 256, 0, stream>>>(eWhh, WPe);
  pack_whh<<<(int)(SZ_WP / 256), 256, 0, stream>>>(dWhh, WPd);
  { dim3 g(H / 32, H / 32); transpose_k<<<g, 256, 0, stream>>>(W2, W2T, H, H); }

  encoder_kernel<<<256, 256, 0, stream>>>(WPe, E, hb, c_buf, enc_out, enc_htags);

  float* D = E;
  { dim3 grid(G4 / 64, (B * S) / 64);
    gemm_nt<0><<<grid, 256, 0, stream>>>(enc_out, dWih, dbias, D, B * S, G4, H); }
  { dim3 grid(H / 64, (B * S) / 64);
    gemm_nt<1><<<grid, 256, 0, stream>>>(enc_out, W1, nullptr, Pt, B * S, H, H); }

  decoder_kernel<<<256, 256, 0, stream>>>(WPd, D, dbias, W2T, Pt, v, c_buf,
                                          enc_out, hb, psbuf,
                                          dec_htags, pstags, out);
  (void)in_sizes; (void)n_in; (void)out_size; (void)ws_size;
}